// Round 2
// 253.791 us; speedup vs baseline: 1.1080x; 1.1080x over previous
//
#include <hip/hip_runtime.h>
#include <hip/hip_bf16.h>
#include <stdint.h>

#define TOKENS 4096
#define IN_F   4096
#define OUT_F  4096
#define NNZ    512

using floatx4 = __attribute__((ext_vector_type(4))) float;
using bf16x8  = __attribute__((ext_vector_type(8))) __bf16;

__device__ __forceinline__ unsigned short f2bf(float f) {
    unsigned int u = __float_as_uint(f);
    u += 0x7FFFu + ((u >> 16) & 1u);   // round-to-nearest-even
    return (unsigned short)(u >> 16);
}

// Fused prep (unchanged; ~110us, next round's target once counters land):
//  blocks [0, 4096)       : build dense bf16 W row in LDS, one coalesced store
//  blocks [4096, 12288)   : convert x fp32 -> bf16, 8 elems/thread
__global__ __launch_bounds__(256) void prep_fused(
        const float* __restrict__ x,
        const float* __restrict__ w,
        const int*   __restrict__ mask,
        unsigned short* __restrict__ Xb,
        unsigned short* __restrict__ Wb) {
    __shared__ unsigned short row[IN_F];   // 8 KB
    const int b = blockIdx.x;
    const int t = threadIdx.x;

    if (b < OUT_F) {
        uint4* rv = (uint4*)row;
        rv[t]       = make_uint4(0u, 0u, 0u, 0u);
        rv[t + 256] = make_uint4(0u, 0u, 0u, 0u);
        __syncthreads();

        const int base = b * NNZ;
#pragma unroll
        for (int e = 0; e < 2; ++e) {
            const int k = t + e * 256;
            const int idx = mask[base + k];
            if (k == 0 || mask[base + k - 1] != idx) {
                float s = w[base + k];
                int j = k + 1;
                while (j < NNZ && mask[base + j] == idx) { s += w[base + j]; ++j; }
                row[idx] = f2bf(s);
            }
        }
        __syncthreads();

        uint4* out = (uint4*)(Wb + (size_t)b * IN_F);
        out[t]       = rv[t];
        out[t + 256] = rv[t + 256];
    } else {
        const int i = (b - OUT_F) * 256 + t;
        const float4* xv = (const float4*)x;
        float4 a = xv[2 * i];
        float4 c = xv[2 * i + 1];
        uint4 o;
        o.x = (unsigned)f2bf(a.x) | ((unsigned)f2bf(a.y) << 16);
        o.y = (unsigned)f2bf(a.z) | ((unsigned)f2bf(a.w) << 16);
        o.z = (unsigned)f2bf(c.x) | ((unsigned)f2bf(c.y) << 16);
        o.w = (unsigned)f2bf(c.z) | ((unsigned)f2bf(c.w) << 16);
        ((uint4*)Xb)[i] = o;
    }
}

// ---------------------------------------------------------------------------
// R2 (resubmit): 256x256 8-phase GEMM (m201 template),
// C[m][n] = sum_k A[m][k]*B[n][k] + bias[n]
//
// 512 thr = 8 waves (2M x 4N), per-wave out 128x64, BK=64, NT=64 K-tiles.
// LDS 128 KiB: As[2]/Bs[2] each 256x64 bf16, double-buffered.
//
// LDS row remap (stage halves == consumption halves):
//   A: LDS rows [  0,128) = "X" = block rows {0-63, 128-191}  (m-frags 0-3)
//      LDS rows [128,256) = "Y" = block rows {64-127, 192-255}(m-frags 4-7)
//   B: LDS rows [  0,128) = "U" = block cols {wn*64+0..31}    (n-frags 0-1)
//      LDS rows [128,256) = "V" = block cols {wn*64+32..63}   (n-frags 2-3)
//
// Bank-conflict swizzle (0-conflict measured in R1): LDS slot (r, s) holds
// global chunk s^(r&7); applied by permuting the per-lane SOURCE address
// (gload_lds dest must stay linear), reads XOR chunk with lm&7.
//
// Per tile t (buf b=t&1), 4 phases, 2 raw s_barrier each, counted vmcnt only:
//   P1: ds A-X(8)+B-U(4); stage A-Y(t+1)->b^1; lgkm(8); bar; lgkm(0); 16 MFMA Q00
//   P2: ds B-V(4);        stage A-X(t+2)->b  ;           bar; lgkm(0); 16 MFMA Q01
//   P3: ds A-Y(8);        stage B-U(t+2)->b  ;           bar; lgkm(0); 16 MFMA Q11
//   P4: (reg reuse);      stage B-V(t+2)->b  ;           bar; 16 MFMA Q10; vmcnt(6)
// Race proof: X/U read only in P1, V in P2, Y in P3 -> each stage target was
// freed by the previous phase's end barrier. vmcnt(6) at tile end leaves
// exactly the 3 t+2 half-tiles in flight => tile t+1 fully landed (per-wave),
// and the following s_barrier makes it cross-wave visible before t+1's reads.
// ---------------------------------------------------------------------------

#define GLL16(src, dst) \
    __builtin_amdgcn_global_load_lds((__attribute__((address_space(1))) void*)(src), \
                                     (__attribute__((address_space(3))) void*)(dst), 16, 0, 0)

__global__ __launch_bounds__(512, 2) void gemm_bt_bias(
        const unsigned short* __restrict__ A,
        const unsigned short* __restrict__ B,
        const float* __restrict__ bias,
        float* __restrict__ C) {
    __shared__ unsigned short As[2][16384];
    __shared__ unsigned short Bs[2][16384];

    const int tid  = threadIdx.x;
    const int wave = tid >> 6;
    const int lane = tid & 63;
    const int lq   = lane >> 4;
    const int lm   = lane & 15;
    const int lm7  = lm & 7;
    const int wm2  = wave >> 2;     // 0..1  (M group)
    const int wn4  = wave & 3;      // 0..3  (N group)

    // XCD-aware bijective swizzle: 256 blocks, 8 XCDs, 32 contiguous per XCD
    const int bid = blockIdx.x;
    const int swz = (bid & 7) * 32 + (bid >> 3);
    const int m0  = (swz >> 4) << 8;
    const int n0  = (swz & 15) << 8;

    // ---- staging source offsets (32-bit element offsets; SGPR base + voffset)
    const int r   = tid >> 3;                        // 0..63
    const int cse = ((tid & 7) ^ (r & 7)) * 8;       // swizzled source chunk
    const int oAX0 = (m0 + r)       * IN_F + cse;
    const int oAX1 = (m0 + 128 + r) * IN_F + cse;
    const int oAY0 = (m0 +  64 + r) * IN_F + cse;
    const int oAY1 = (m0 + 192 + r) * IN_F + cse;
    const int bc_  = (r >> 5) * 64 + (r & 31);
    const int oBU0 = (n0 + bc_)        * IN_F + cse;
    const int oBU1 = (n0 + 128 + bc_)  * IN_F + cse;
    const int oBV0 = (n0 +  32 + bc_)  * IN_F + cse;
    const int oBV1 = (n0 + 160 + bc_)  * IN_F + cse;
    const int wofs = wave * 512;                     // wave-uniform LDS dest

#define STAGE_AX(bb, kk) { GLL16(A + oAX0 + (kk), &As[bb][        wofs]); \
                           GLL16(A + oAX1 + (kk), &As[bb][ 4096 + wofs]); }
#define STAGE_AY(bb, kk) { GLL16(A + oAY0 + (kk), &As[bb][ 8192 + wofs]); \
                           GLL16(A + oAY1 + (kk), &As[bb][12288 + wofs]); }
#define STAGE_BU(bb, kk) { GLL16(B + oBU0 + (kk), &Bs[bb][        wofs]); \
                           GLL16(B + oBU1 + (kk), &Bs[bb][ 4096 + wofs]); }
#define STAGE_BV(bb, kk) { GLL16(B + oBV0 + (kk), &Bs[bb][ 8192 + wofs]); \
                           GLL16(B + oBV1 + (kk), &Bs[bb][12288 + wofs]); }

    // ---- ds_read offsets (ushort units)
    const int ck0 = (lq ^ lm7) * 8;
    const int ck1 = ck0 ^ 32;
    const int aX  = (wm2 * 64 + lm) * 64;
    const int aY  = aX + 8192;
    const int bU  = (wn4 * 32 + lm) * 64;
    const int bV  = bU + 8192;

    floatx4 acc[8][4] = {};
    bf16x8 af[4][2], bu[2][2], bv[2][2];

    // ---- prologue: tile0 complete (8 loads) + tile1 partial (6 loads)
    STAGE_AX(0, 0); STAGE_BU(0, 0); STAGE_BV(0, 0); STAGE_AY(0, 0);
    STAGE_AX(1, 64); STAGE_BU(1, 64); STAGE_BV(1, 64);
    asm volatile("s_waitcnt vmcnt(6)" ::: "memory");
    __builtin_amdgcn_s_barrier();

#define TILE_STEP(T, BB)                                                          \
    {                                                                             \
        const unsigned short* sA = As[BB];                                        \
        const unsigned short* sB = Bs[BB];                                        \
        const int kk1 = ((T) + 1 < 64 ? (T) + 1 : 63) * 64;                       \
        const int kk2 = ((T) + 2 < 64 ? (T) + 2 : 63) * 64;                       \
        /* ---- phase 1: Q00 ---- */                                              \
        _Pragma("unroll")                                                         \
        for (int mi = 0; mi < 4; ++mi) {                                          \
            af[mi][0] = *(const bf16x8*)(sA + aX + mi * 1024 + ck0);              \
            af[mi][1] = *(const bf16x8*)(sA + aX + mi * 1024 + ck1);              \
        }                                                                         \
        _Pragma("unroll")                                                         \
        for (int ni = 0; ni < 2; ++ni) {                                          \
            bu[ni][0] = *(const bf16x8*)(sB + bU + ni * 1024 + ck0);              \
            bu[ni][1] = *(const bf16x8*)(sB + bU + ni * 1024 + ck1);              \
        }                                                                         \
        STAGE_AY((BB) ^ 1, kk1);                                                  \
        asm volatile("s_waitcnt lgkmcnt(8)" ::: "memory");                        \
        __builtin_amdgcn_s_barrier();                                             \
        asm volatile("s_waitcnt lgkmcnt(0)" ::: "memory");                        \
        __builtin_amdgcn_s_setprio(1);                                            \
        _Pragma("unroll")                                                         \
        for (int mi = 0; mi < 4; ++mi)                                            \
            _Pragma("unroll")                                                     \
            for (int ni = 0; ni < 2; ++ni) {                                      \
                acc[mi][ni] = __builtin_amdgcn_mfma_f32_16x16x32_bf16(            \
                    af[mi][0], bu[ni][0], acc[mi][ni], 0, 0, 0);                  \
                acc[mi][ni] = __builtin_amdgcn_mfma_f32_16x16x32_bf16(            \
                    af[mi][1], bu[ni][1], acc[mi][ni], 0, 0, 0);                  \
            }                                                                     \
        __builtin_amdgcn_s_setprio(0);                                            \
        __builtin_amdgcn_s_barrier();                                             \
        /* ---- phase 2: Q01 ---- */                                              \
        _Pragma("unroll")                                                         \
        for (int ni = 0; ni < 2; ++ni) {                                          \
            bv[ni][0] = *(const bf16x8*)(sB + bV + ni * 1024 + ck0);              \
            bv[ni][1] = *(const bf16x8*)(sB + bV + ni * 1024 + ck1);              \
        }                                                                         \
        STAGE_AX((BB), kk2);                                                      \
        __builtin_amdgcn_s_barrier();                                             \
        asm volatile("s_waitcnt lgkmcnt(0)" ::: "memory");                        \
        __builtin_amdgcn_s_setprio(1);                                            \
        _Pragma("unroll")                                                         \
        for (int mi = 0; mi < 4; ++mi)                                            \
            _Pragma("unroll")                                                     \
            for (int ni = 0; ni < 2; ++ni) {                                      \
                acc[mi][2 + ni] = __builtin_amdgcn_mfma_f32_16x16x32_bf16(        \
                    af[mi][0], bv[ni][0], acc[mi][2 + ni], 0, 0, 0);              \
                acc[mi][2 + ni] = __builtin_amdgcn_mfma_f32_16x16x32_bf16(        \
                    af[mi][1], bv[ni][1], acc[mi][2 + ni], 0, 0, 0);              \
            }                                                                     \
        __builtin_amdgcn_s_setprio(0);                                            \
        __builtin_amdgcn_s_barrier();                                             \
        /* ---- phase 3: Q11 ---- */                                              \
        _Pragma("unroll")                                                         \
        for (int mi = 0; mi < 4; ++mi) {                                          \
            af[mi][0] = *(const bf16x8*)(sA + aY + mi * 1024 + ck0);              \
            af[mi][1] = *(const bf16x8*)(sA + aY + mi * 1024 + ck1);              \
        }                                                                         \
        STAGE_BU((BB), kk2);                                                      \
        __builtin_amdgcn_s_barrier();                                             \
        asm volatile("s_waitcnt lgkmcnt(0)" ::: "memory");                        \
        __builtin_amdgcn_s_setprio(1);                                            \
        _Pragma("unroll")                                                         \
        for (int mi = 0; mi < 4; ++mi)                                            \
            _Pragma("unroll")                                                     \
            for (int ni = 0; ni < 2; ++ni) {                                      \
                acc[4 + mi][2 + ni] = __builtin_amdgcn_mfma_f32_16x16x32_bf16(    \
                    af[mi][0], bv[ni][0], acc[4 + mi][2 + ni], 0, 0, 0);          \
                acc[4 + mi][2 + ni] = __builtin_amdgcn_mfma_f32_16x16x32_bf16(    \
                    af[mi][1], bv[ni][1], acc[4 + mi][2 + ni], 0, 0, 0);          \
            }                                                                     \
        __builtin_amdgcn_s_setprio(0);                                            \
        __builtin_amdgcn_s_barrier();                                             \
        /* ---- phase 4: Q10 (pure register reuse) ---- */                        \
        STAGE_BV((BB), kk2);                                                      \
        __builtin_amdgcn_s_barrier();                                             \
        __builtin_amdgcn_s_setprio(1);                                            \
        _Pragma("unroll")                                                         \
        for (int mi = 0; mi < 4; ++mi)                                            \
            _Pragma("unroll")                                                     \
            for (int ni = 0; ni < 2; ++ni) {                                      \
                acc[4 + mi][ni] = __builtin_amdgcn_mfma_f32_16x16x32_bf16(        \
                    af[mi][0], bu[ni][0], acc[4 + mi][ni], 0, 0, 0);              \
                acc[4 + mi][ni] = __builtin_amdgcn_mfma_f32_16x16x32_bf16(        \
                    af[mi][1], bu[ni][1], acc[4 + mi][ni], 0, 0, 0);              \
            }                                                                     \
        __builtin_amdgcn_s_setprio(0);                                            \
        asm volatile("s_waitcnt vmcnt(6)" ::: "memory");                          \
        __builtin_amdgcn_s_barrier();                                             \
    }

    for (int tt = 0; tt < 32; ++tt) {
        TILE_STEP(2 * tt,     0);
        TILE_STEP(2 * tt + 1, 1);
    }

    // ---- epilogue: C/D layout col = lane&15, row = (lane>>4)*4 + reg  [m89]
#pragma unroll
    for (int ni = 0; ni < 4; ++ni) {
        const int n = n0 + wn4 * 64 + ni * 16 + lm;
        const float bb = bias[n];
#pragma unroll
        for (int mi = 0; mi < 8; ++mi) {
            const int mb = m0 + wm2 * 128 + mi * 16 + lq * 4;
#pragma unroll
            for (int rr = 0; rr < 4; ++rr) {
                C[(size_t)(mb + rr) * OUT_F + n] = acc[mi][ni][rr] + bb;
            }
        }
    }
}

extern "C" void kernel_launch(void* const* d_in, const int* in_sizes, int n_in,
                              void* d_out, int out_size, void* d_ws, size_t ws_size,
                              hipStream_t stream) {
    const float* x    = (const float*)d_in[0];   // [4096,4096] fp32
    const float* w    = (const float*)d_in[1];   // [4096,512]  fp32
    const int*   mask = (const int*)d_in[2];     // [4096,512]  int32 (sorted rows)
    const float* bias = (const float*)d_in[3];   // [4096]      fp32
    float* out = (float*)d_out;                  // [4096,4096] fp32

    unsigned short* Xb = (unsigned short*)d_ws;                 // 32 MiB
    unsigned short* Wb = Xb + (size_t)TOKENS * IN_F;            // 32 MiB

    prep_fused<<<OUT_F + 8192, 256, 0, stream>>>(x, w, mask, Xb, Wb);
    gemm_bt_bias<<<dim3(256), dim3(512), 0, stream>>>(Xb, Wb, bias, out);
}